// Round 6
// baseline (56997.766 us; speedup 1.0000x reference)
//
#include <hip/hip_runtime.h>
#include <math.h>

// Problem constants (must match reference)
constexpr int B = 8, N = 32768, C = 3, H = 256, R = 64, NHID = 4;
constexpr int PTS   = 32;    // points per block
constexpr int BLOCK = 256;   // 8 threads cooperate per point (o-range 32 each)
constexpr int PADA  = 257;   // LDS act row stride (conflict-free)

// Workspace (floats):
//   dwh : [NHID][B][H][H]  materialized fp32 dW (np order)   = 2,097,152
//   dw0 : [B][H][3]        layer-0 dW                        =     6,144
//   fbe : [NHID+1][B][H]   materialized fp32 FiLM bias       =    10,240
constexpr size_t OFS_DWH = 0;
constexpr size_t OFS_DW0 = (size_t)NHID * B * H * H;
constexpr size_t OFS_FBE = OFS_DW0 + (size_t)B * H * 3;
// total ~8.45 MB (within the round-1-proven ws footprint)

// ---------------------------------------------------------------------------
// fdlibm fp64 sine, error ~1e-16. Models numpy's float32 sin as
// (float)sin((double)x): correctly-rounded double sine, rounded to fp32.
// Valid for |x| <= ~1e3 (2-term Cody-Waite pi/2 reduction).
// ---------------------------------------------------------------------------
__device__ __forceinline__ double sin_d(double x)
{
    const double INV_PIO2 = 6.36619772367581382433e-01;
    const double P1  = 1.57079632673412561417e+00;
    const double P1T = 6.07710050650619224932e-11;
    double fn = rint(x * INV_PIO2);
    int n = (int)fn;
    double r = fma(-fn, P1, x);
    r = fma(-fn, P1T, r);
    double z = r * r;
    double ps = fma(z, 1.58969099521155010221e-10, -2.50507602534068634195e-08);
    ps = fma(z, ps, 2.75573137070700676789e-06);
    ps = fma(z, ps, -1.98412698298579493134e-04);
    ps = fma(z, ps, 8.33333333332248946124e-03);
    ps = fma(z, ps, -1.66666666666666324348e-01);
    double s = fma(r * z, ps, r);
    double pc = fma(z, -1.13596475577881948265e-11, 2.08757232129817482790e-09);
    pc = fma(z, pc, -2.75573143513906633035e-07);
    pc = fma(z, pc, 2.48015872894767294178e-05);
    pc = fma(z, pc, -1.38888888888741095749e-03);
    pc = fma(z, pc, 4.16666666666666019037e-02);
    double c = fma(z * z, pc, fma(z, -0.5, 1.0));
    int k = n & 3;
    double v = (k & 1) ? c : s;
    return (k & 2) ? -v : v;
}

__device__ __forceinline__ float npsinf(float xf)
{
    return (float)sin_d((double)xf);
}

// ---------------------------------------------------------------------------
// Materialize np's fp32 intermediates EXACTLY:
//   dW[l][b][o][i] = sum_r (U[l+1][o][r]*lat[b][r]) * V[l][i][r]   (fp32, r asc, fma)
//   dW0[b][o][c]   = sum_r (U[0][o][r]*lat[b][r]) * V0[c][r]
//   fb[lidx][b][o] = sum_r fma(lat[b][r], HB[lidx][o][r])          (sgemm model)
// ---------------------------------------------------------------------------
__global__ void precomp_np(const float* __restrict__ lat, const float* __restrict__ U,
                           const float* __restrict__ V0,  const float* __restrict__ Vh,
                           const float* __restrict__ HB,
                           float* __restrict__ dwh, float* __restrict__ dw0,
                           float* __restrict__ fbe)
{
    int bi = blockIdx.x;
    int o  = threadIdx.x;
    if (bi < NHID * B) {
        int l = bi >> 3, b = bi & 7;
        const float* Uo = U + ((size_t)(l + 1) * H + o) * R;
        const float* lb = lat + b * R;
        float t[R];
        #pragma unroll
        for (int r = 0; r < R; ++r) t[r] = Uo[r] * lb[r];   // rounded fp32 mul
        const float* Vb = Vh + (size_t)l * H * R;
        float* dst = dwh + ((size_t)(l * B + b) * H + o) * H;
        for (int i = 0; i < H; ++i) {
            const float* Vi = Vb + (size_t)i * R;
            float acc = 0.f;
            #pragma unroll
            for (int r = 0; r < R; ++r) acc = fmaf(t[r], Vi[r], acc);
            dst[i] = acc;
        }
    } else if (bi < NHID * B + B) {
        int b = bi - NHID * B;
        const float* Uo = U + (size_t)o * R;        // U[0][o][:]
        const float* lb = lat + b * R;
        float t[R];
        #pragma unroll
        for (int r = 0; r < R; ++r) t[r] = Uo[r] * lb[r];
        #pragma unroll
        for (int c = 0; c < C; ++c) {
            float acc = 0.f;
            #pragma unroll
            for (int r = 0; r < R; ++r) acc = fmaf(t[r], V0[c * R + r], acc);
            dw0[((size_t)b * H + o) * 3 + c] = acc;
        }
    } else {
        int b = bi - NHID * B - B;
        const float* lb = lat + b * R;
        for (int lidx = 0; lidx < NHID + 1; ++lidx) {
            const float* hb = HB + ((size_t)lidx * H + o) * R;
            float acc = 0.f;
            #pragma unroll
            for (int r = 0; r < R; ++r) acc = fmaf(lb[r], hb[r], acc);
            fbe[((size_t)lidx * B + b) * H + o] = acc;
        }
    }
}

// ---------------------------------------------------------------------------
// np-replica forward. Per point, per output o (np sgemm semantics):
//   lin   = sum_i fmaf(a[i], W[o][i])   (single acc, i ascending from 0)
//   lin  += b[o]                         (separate rounded add)
//   delta = sum_i fmaf(a[i], dW[o][i])
//   z     = (lin + delta) + fb
//   a'    = npsinf(30.0f * z)
// NO folding of W+dW — np computes two GEMMs and adds the fp32 results.
// 256 threads: 32 points x 8 o-slices. Double-buffered LDS acts (exact fp32).
// ---------------------------------------------------------------------------
__launch_bounds__(BLOCK)
__global__ void siren_np(const float* __restrict__ coords,
                         const float* __restrict__ Wf, const float* __restrict__ bf,
                         const float* __restrict__ Wh, const float* __restrict__ bh,
                         const float* __restrict__ Wl, const float* __restrict__ bl,
                         const float* __restrict__ dwh, const float* __restrict__ dw0,
                         const float* __restrict__ fbe,
                         float* __restrict__ out)
{
    __shared__ float abuf[2][PTS * PADA];   // 65,792 B -> 2 blocks/CU
    const int tid = threadIdx.x;
    const int pl = tid >> 3, q = tid & 7, obase = q * 32;
    const int p  = blockIdx.x * PTS + pl;   // global point index = b*N + n
    const int b  = p >> 15;                 // N = 2^15

    const float x0 = coords[(size_t)p * 3 + 0];
    const float x1 = coords[(size_t)p * 3 + 1];
    const float x2 = coords[(size_t)p * 3 + 2];

    // ---- layer 0 ----
    {
        const float* fb0 = fbe + (size_t)(0 * B + b) * H;
        for (int jo = 0; jo < 32; ++jo) {
            int o = obase + jo;
            float lin = 0.f;
            lin = fmaf(x0, Wf[o * 3 + 0], lin);
            lin = fmaf(x1, Wf[o * 3 + 1], lin);
            lin = fmaf(x2, Wf[o * 3 + 2], lin);
            lin = lin + bf[o];
            const float* dwo = dw0 + ((size_t)b * H + o) * 3;
            float dl = 0.f;
            dl = fmaf(x0, dwo[0], dl);
            dl = fmaf(x1, dwo[1], dl);
            dl = fmaf(x2, dwo[2], dl);
            float z = (lin + dl) + fb0[o];
            abuf[0][pl * PADA + o] = npsinf(30.0f * z);
        }
    }
    __syncthreads();

    // ---- hidden layers ----
    int cur = 0;
    for (int l = 0; l < NHID; ++l) {
        const float* A  = abuf[cur];
        float*       Ao = abuf[cur ^ 1];
        const float* Wb = Wh + (size_t)l * H * H;
        const float* Db = dwh + (size_t)(l * B + b) * H * H;
        const float* be = bh + (size_t)l * H;
        const float* fbl = fbe + (size_t)((l + 1) * B + b) * H;
        for (int jo = 0; jo < 32; jo += 4) {
            const int o = obase + jo;
            const float* w0 = Wb + (size_t)(o + 0) * H;
            const float* w1 = Wb + (size_t)(o + 1) * H;
            const float* w2 = Wb + (size_t)(o + 2) * H;
            const float* w3 = Wb + (size_t)(o + 3) * H;
            const float* d0 = Db + (size_t)(o + 0) * H;
            const float* d1 = Db + (size_t)(o + 1) * H;
            const float* d2 = Db + (size_t)(o + 2) * H;
            const float* d3 = Db + (size_t)(o + 3) * H;
            float l0 = 0.f, l1 = 0.f, l2 = 0.f, l3 = 0.f;
            float e0 = 0.f, e1 = 0.f, e2 = 0.f, e3 = 0.f;
            const float* ar = A + pl * PADA;
            #pragma unroll 4
            for (int i = 0; i < H; ++i) {          // i ASCENDING, single acc = sgemm
                float ai = ar[i];
                l0 = fmaf(ai, w0[i], l0); e0 = fmaf(ai, d0[i], e0);
                l1 = fmaf(ai, w1[i], l1); e1 = fmaf(ai, d1[i], e1);
                l2 = fmaf(ai, w2[i], l2); e2 = fmaf(ai, d2[i], e2);
                l3 = fmaf(ai, w3[i], l3); e3 = fmaf(ai, d3[i], e3);
            }
            Ao[pl * PADA + o + 0] = npsinf(30.0f * (((l0 + be[o + 0]) + e0) + fbl[o + 0]));
            Ao[pl * PADA + o + 1] = npsinf(30.0f * (((l1 + be[o + 1]) + e1) + fbl[o + 1]));
            Ao[pl * PADA + o + 2] = npsinf(30.0f * (((l2 + be[o + 2]) + e2) + fbl[o + 2]));
            Ao[pl * PADA + o + 3] = npsinf(30.0f * (((l3 + be[o + 3]) + e3) + fbl[o + 3]));
        }
        __syncthreads();
        cur ^= 1;
    }

    // ---- final projection (gain ~1: split reduction is fine) ----
    {
        const float* ar = abuf[cur] + pl * PADA + q * 32;
        const float* wl = Wl + q * 32;
        float s = 0.f;
        #pragma unroll 8
        for (int t = 0; t < 32; ++t) s = fmaf(ar[t], wl[t], s);
        s += __shfl_xor(s, 1);
        s += __shfl_xor(s, 2);
        s += __shfl_xor(s, 4);
        if (q == 0) out[p] = s + bl[0];
    }
}

// ---------------------------------------------------------------------------
extern "C" void kernel_launch(void* const* d_in, const int* in_sizes, int n_in,
                              void* d_out, int out_size, void* d_ws, size_t ws_size,
                              hipStream_t stream)
{
    const float* coords = (const float*)d_in[0];
    const float* lat    = (const float*)d_in[1];
    const float* Wf     = (const float*)d_in[2];
    const float* bf     = (const float*)d_in[3];
    const float* Wh     = (const float*)d_in[4];
    const float* bh     = (const float*)d_in[5];
    const float* Wl     = (const float*)d_in[6];
    const float* bl     = (const float*)d_in[7];
    const float* U      = (const float*)d_in[8];
    const float* V0     = (const float*)d_in[9];
    const float* Vh     = (const float*)d_in[10];
    const float* HB     = (const float*)d_in[11];

    float* ws  = (float*)d_ws;   // ~8.45 MB
    float* dwh = ws + OFS_DWH;
    float* dw0 = ws + OFS_DW0;
    float* fbe = ws + OFS_FBE;

    precomp_np<<<NHID * B + B + B, H, 0, stream>>>(lat, U, V0, Vh, HB, dwh, dw0, fbe);
    siren_np<<<(B * N) / PTS, BLOCK, 0, stream>>>(coords, Wf, bf, Wh, bh, Wl, bl,
                                                  dwh, dw0, fbe, (float*)d_out);
}

// Round 7
// 3400.106 us; speedup vs baseline: 16.7635x; 16.7635x over previous
//
#include <hip/hip_runtime.h>
#include <math.h>

// Problem constants (must match reference)
constexpr int B = 8, N = 32768, C = 3, H = 256, R = 64, NHID = 4;
constexpr int PTS   = 32;    // points per block
constexpr int BLOCK = 256;   // 64 o-lanes (4 outputs each) x 4 point-groups (8 pts each)
constexpr int PADA  = 260;   // LDS act row stride (multiple of 4 -> aligned float4)

// Workspace (floats), total ~9.46 MB:
//   dwT : [NHID][B][H][H]  dW transposed [i][o]  (np-exact values)  = 2,097,152
//   wT  : [NHID][H][H]     W_hid transposed [i][o] (bit-exact copy) =   262,144
//   dw0 : [B][H][3]        layer-0 dW                               =     6,144
//   fbe : [NHID+1][B][H]   FiLM bias                                =    10,240
constexpr size_t OFS_DWT = 0;
constexpr size_t OFS_WT  = (size_t)NHID * B * H * H;
constexpr size_t OFS_DW0 = OFS_WT + (size_t)NHID * H * H;
constexpr size_t OFS_FBE = OFS_DW0 + (size_t)B * H * 3;

// ---------------------------------------------------------------------------
// fdlibm fp64 sine, error ~1e-16. Models numpy float32 sin as
// (float)sin((double)x). Valid for |x| <= ~1e3 (2-term Cody-Waite).
// ---------------------------------------------------------------------------
__device__ __forceinline__ double sin_d(double x)
{
    const double INV_PIO2 = 6.36619772367581382433e-01;
    const double P1  = 1.57079632673412561417e+00;
    const double P1T = 6.07710050650619224932e-11;
    double fn = rint(x * INV_PIO2);
    int n = (int)fn;
    double r = fma(-fn, P1, x);
    r = fma(-fn, P1T, r);
    double z = r * r;
    double ps = fma(z, 1.58969099521155010221e-10, -2.50507602534068634195e-08);
    ps = fma(z, ps, 2.75573137070700676789e-06);
    ps = fma(z, ps, -1.98412698298579493134e-04);
    ps = fma(z, ps, 8.33333333332248946124e-03);
    ps = fma(z, ps, -1.66666666666666324348e-01);
    double s = fma(r * z, ps, r);
    double pc = fma(z, -1.13596475577881948265e-11, 2.08757232129817482790e-09);
    pc = fma(z, pc, -2.75573143513906633035e-07);
    pc = fma(z, pc, 2.48015872894767294178e-05);
    pc = fma(z, pc, -1.38888888888741095749e-03);
    pc = fma(z, pc, 4.16666666666666019037e-02);
    double c = fma(z * z, pc, fma(z, -0.5, 1.0));
    int k = n & 3;
    double v = (k & 1) ? c : s;
    return (k & 2) ? -v : v;
}

__device__ __forceinline__ float npsinf(float xf)
{
    return (float)sin_d((double)xf);
}

// ---------------------------------------------------------------------------
// Materialize np's fp32 intermediates EXACTLY (same arithmetic as round 6,
// dW stored TRANSPOSED [i][o] for coalesced forward reads):
// ---------------------------------------------------------------------------
__global__ void precomp_np(const float* __restrict__ lat, const float* __restrict__ U,
                           const float* __restrict__ V0,  const float* __restrict__ Vh,
                           const float* __restrict__ HB,
                           float* __restrict__ dwT, float* __restrict__ dw0,
                           float* __restrict__ fbe)
{
    int bi = blockIdx.x;
    int o  = threadIdx.x;
    if (bi < NHID * B) {
        int l = bi >> 3, b = bi & 7;
        const float* Uo = U + ((size_t)(l + 1) * H + o) * R;
        const float* lb = lat + b * R;
        float t[R];
        #pragma unroll
        for (int r = 0; r < R; ++r) t[r] = Uo[r] * lb[r];   // rounded fp32 mul
        const float* Vb = Vh + (size_t)l * H * R;
        float* dst = dwT + (size_t)(l * B + b) * H * H;     // [i][o]
        for (int i = 0; i < H; ++i) {
            const float* Vi = Vb + (size_t)i * R;
            float acc = 0.f;
            #pragma unroll
            for (int r = 0; r < R; ++r) acc = fmaf(t[r], Vi[r], acc);
            dst[(size_t)i * H + o] = acc;                   // coalesced over o
        }
    } else if (bi < NHID * B + B) {
        int b = bi - NHID * B;
        const float* Uo = U + (size_t)o * R;        // U[0][o][:]
        const float* lb = lat + b * R;
        float t[R];
        #pragma unroll
        for (int r = 0; r < R; ++r) t[r] = Uo[r] * lb[r];
        #pragma unroll
        for (int c = 0; c < C; ++c) {
            float acc = 0.f;
            #pragma unroll
            for (int r = 0; r < R; ++r) acc = fmaf(t[r], V0[c * R + r], acc);
            dw0[((size_t)b * H + o) * 3 + c] = acc;
        }
    } else {
        int b = bi - NHID * B - B;
        const float* lb = lat + b * R;
        for (int lidx = 0; lidx < NHID + 1; ++lidx) {
            const float* hb = HB + ((size_t)lidx * H + o) * R;
            float acc = 0.f;
            #pragma unroll
            for (int r = 0; r < R; ++r) acc = fmaf(lb[r], hb[r], acc);
            fbe[((size_t)lidx * B + b) * H + o] = acc;
        }
    }
}

// Pure bit-exact transpose: wT[l][i][o] = W_hid[l][o][i]
__global__ void transposeW(const float* __restrict__ Wh, float* __restrict__ wT)
{
    int li = blockIdx.x;           // l*H + i
    int o  = threadIdx.x;
    int l = li >> 8, i = li & 255;
    wT[(size_t)li * H + o] = Wh[((size_t)l * H + o) * H + i];
}

// ---------------------------------------------------------------------------
// np-replica forward, coalesced layout. Thread t: og=t&63 owns 4 outputs
// o=og*4..+3; pg=t>>6 owns 8 points. Per i: 2 coalesced float4 weight loads
// (wave reads 1KB contiguous), 2 float4 LDS act broadcasts per point-chunk,
// 64 independent FMA chains. Arithmetic per output is BIT-IDENTICAL to
// round 6: single fp32 accumulator, i ascending, fmaf; then
// ((lin+b)+delta)+fb, *30.0f, double-rounded sin.
// ---------------------------------------------------------------------------
__launch_bounds__(BLOCK)
__global__ void siren_np(const float* __restrict__ coords,
                         const float* __restrict__ Wf, const float* __restrict__ bf,
                         const float* __restrict__ bh,
                         const float* __restrict__ Wl, const float* __restrict__ bl,
                         const float* __restrict__ wT, const float* __restrict__ dwT,
                         const float* __restrict__ dw0, const float* __restrict__ fbe,
                         float* __restrict__ out)
{
    __shared__ __align__(16) float abuf[2][PTS * PADA];   // 66,560 B
    __shared__ float cbuf[PTS * 3 + 1];                    // coords tile
    const int tid = threadIdx.x;
    const int og = tid & 63, pg = tid >> 6;
    const int o0 = og * 4, pbase = pg * 8;
    const int p0 = blockIdx.x * PTS;          // global point base
    const int b  = p0 >> 15;                  // N = 2^15; all 32 pts same batch

    if (tid < PTS * 3) cbuf[tid] = coords[(size_t)p0 * 3 + tid];
    __syncthreads();

    // ---- layer 0 ----
    {
        const float* fb0 = fbe + (size_t)(0 * B + b) * H;
        #pragma unroll
        for (int j = 0; j < 4; ++j) {
            const int o = o0 + j;
            const float wf0 = Wf[o * 3 + 0], wf1 = Wf[o * 3 + 1], wf2 = Wf[o * 3 + 2];
            const float* dwo = dw0 + ((size_t)b * H + o) * 3;
            const float dd0 = dwo[0], dd1 = dwo[1], dd2 = dwo[2];
            const float bo = bf[o], fo = fb0[o];
            #pragma unroll
            for (int k = 0; k < 8; ++k) {
                const float x0 = cbuf[(pbase + k) * 3 + 0];
                const float x1 = cbuf[(pbase + k) * 3 + 1];
                const float x2 = cbuf[(pbase + k) * 3 + 2];
                float lin = 0.f;
                lin = fmaf(x0, wf0, lin);
                lin = fmaf(x1, wf1, lin);
                lin = fmaf(x2, wf2, lin);
                lin = lin + bo;
                float dl = 0.f;
                dl = fmaf(x0, dd0, dl);
                dl = fmaf(x1, dd1, dl);
                dl = fmaf(x2, dd2, dl);
                float z = (lin + dl) + fo;
                abuf[0][(pbase + k) * PADA + o] = npsinf(30.0f * z);
            }
        }
    }
    __syncthreads();

    // ---- hidden layers ----
    int cur = 0;
    for (int l = 0; l < NHID; ++l) {
        const float* A  = abuf[cur];
        float*       Ao = abuf[cur ^ 1];
        const float4* Wt4 = (const float4*)(wT  + (size_t)l * H * H);
        const float4* Dt4 = (const float4*)(dwT + (size_t)(l * B + b) * H * H);

        float lacc[4][8], eacc[4][8];
        #pragma unroll
        for (int j = 0; j < 4; ++j)
            #pragma unroll
            for (int k = 0; k < 8; ++k) { lacc[j][k] = 0.f; eacc[j][k] = 0.f; }

        for (int i0 = 0; i0 < H; i0 += 4) {
            float4 av[8];
            #pragma unroll
            for (int k = 0; k < 8; ++k)
                av[k] = *(const float4*)(&A[(pbase + k) * PADA + i0]);
            #pragma unroll
            for (int ii = 0; ii < 4; ++ii) {        // i = i0+ii ASCENDING
                const int i = i0 + ii;
                const float4 w4 = Wt4[(size_t)i * 64 + og];
                const float4 d4 = Dt4[(size_t)i * 64 + og];
                const float wj[4] = {w4.x, w4.y, w4.z, w4.w};
                const float dj[4] = {d4.x, d4.y, d4.z, d4.w};
                #pragma unroll
                for (int k = 0; k < 8; ++k) {
                    const float ai = (&av[k].x)[ii];
                    #pragma unroll
                    for (int j = 0; j < 4; ++j) {
                        lacc[j][k] = fmaf(ai, wj[j], lacc[j][k]);
                        eacc[j][k] = fmaf(ai, dj[j], eacc[j][k]);
                    }
                }
            }
        }
        __syncthreads();   // all A reads complete before Ao overwrite next iter
        {
            const float* be  = bh + (size_t)l * H;
            const float* fbl = fbe + (size_t)((l + 1) * B + b) * H;
            #pragma unroll
            for (int j = 0; j < 4; ++j) {
                const int o = o0 + j;
                const float bo = be[o], fo = fbl[o];
                #pragma unroll
                for (int k = 0; k < 8; ++k) {
                    float z = ((lacc[j][k] + bo) + eacc[j][k]) + fo;
                    Ao[(pbase + k) * PADA + o] = npsinf(30.0f * z);
                }
            }
        }
        __syncthreads();
        cur ^= 1;
    }

    // ---- final projection (gain ~1): same arithmetic as round 6 ----
    {
        const int pl = tid >> 3, q = tid & 7;
        const float* ar = abuf[cur] + pl * PADA + q * 32;
        const float* wl = Wl + q * 32;
        float s = 0.f;
        #pragma unroll 8
        for (int t = 0; t < 32; ++t) s = fmaf(ar[t], wl[t], s);
        s += __shfl_xor(s, 1);
        s += __shfl_xor(s, 2);
        s += __shfl_xor(s, 4);
        if (q == 0) out[p0 + pl] = s + bl[0];
    }
}

// ---------------------------------------------------------------------------
extern "C" void kernel_launch(void* const* d_in, const int* in_sizes, int n_in,
                              void* d_out, int out_size, void* d_ws, size_t ws_size,
                              hipStream_t stream)
{
    const float* coords = (const float*)d_in[0];
    const float* lat    = (const float*)d_in[1];
    const float* Wf     = (const float*)d_in[2];
    const float* bf     = (const float*)d_in[3];
    const float* Wh     = (const float*)d_in[4];
    const float* bh     = (const float*)d_in[5];
    const float* Wl     = (const float*)d_in[6];
    const float* bl     = (const float*)d_in[7];
    const float* U      = (const float*)d_in[8];
    const float* V0     = (const float*)d_in[9];
    const float* Vh     = (const float*)d_in[10];
    const float* HB     = (const float*)d_in[11];

    float* ws  = (float*)d_ws;   // ~9.46 MB
    float* dwT = ws + OFS_DWT;
    float* wT  = ws + OFS_WT;
    float* dw0 = ws + OFS_DW0;
    float* fbe = ws + OFS_FBE;

    precomp_np<<<NHID * B + B + B, H, 0, stream>>>(lat, U, V0, Vh, HB, dwT, dw0, fbe);
    transposeW<<<NHID * H, H, 0, stream>>>(Wh, wT);
    siren_np<<<(B * N) / PTS, BLOCK, 0, stream>>>(coords, Wf, bf, bh, Wl, bl,
                                                  wT, dwT, dw0, fbe, (float*)d_out);
}

// Round 8
// 3398.420 us; speedup vs baseline: 16.7718x; 1.0005x over previous
//
#include <hip/hip_runtime.h>
#include <math.h>

// Problem constants (must match reference)
constexpr int B = 8, N = 32768, C = 3, H = 256, R = 64, NHID = 4;
constexpr int PTS   = 32;    // points per block
constexpr int BLOCK = 256;   // 64 o-lanes (4 outputs each) x 4 point-groups (8 pts each)
constexpr int PADA  = 260;   // LDS act row stride (multiple of 4 -> aligned float4)

// Workspace (floats), total ~9.46 MB:
//   dwT : [NHID][B][H][H]  dW transposed [i][o]  (np-exact values)  = 2,097,152
//   wT  : [NHID][H][H]     W_hid transposed [i][o] (bit-exact copy) =   262,144
//   dw0 : [B][H][3]        layer-0 dW                               =     6,144
//   fbe : [NHID+1][B][H]   FiLM bias                                =    10,240
constexpr size_t OFS_DWT = 0;
constexpr size_t OFS_WT  = (size_t)NHID * B * H * H;
constexpr size_t OFS_DW0 = OFS_WT + (size_t)NHID * H * H;
constexpr size_t OFS_FBE = OFS_DW0 + (size_t)B * H * 3;

// ---------------------------------------------------------------------------
// fdlibm fp64 sine, error ~1e-16. Models numpy float32 sin as
// (float)sin((double)x). Valid for |x| <= ~1e3 (2-term Cody-Waite).
// ---------------------------------------------------------------------------
__device__ __forceinline__ double sin_d(double x)
{
    const double INV_PIO2 = 6.36619772367581382433e-01;
    const double P1  = 1.57079632673412561417e+00;
    const double P1T = 6.07710050650619224932e-11;
    double fn = rint(x * INV_PIO2);
    int n = (int)fn;
    double r = fma(-fn, P1, x);
    r = fma(-fn, P1T, r);
    double z = r * r;
    double ps = fma(z, 1.58969099521155010221e-10, -2.50507602534068634195e-08);
    ps = fma(z, ps, 2.75573137070700676789e-06);
    ps = fma(z, ps, -1.98412698298579493134e-04);
    ps = fma(z, ps, 8.33333333332248946124e-03);
    ps = fma(z, ps, -1.66666666666666324348e-01);
    double s = fma(r * z, ps, r);
    double pc = fma(z, -1.13596475577881948265e-11, 2.08757232129817482790e-09);
    pc = fma(z, pc, -2.75573143513906633035e-07);
    pc = fma(z, pc, 2.48015872894767294178e-05);
    pc = fma(z, pc, -1.38888888888741095749e-03);
    pc = fma(z, pc, 4.16666666666666019037e-02);
    double c = fma(z * z, pc, fma(z, -0.5, 1.0));
    int k = n & 3;
    double v = (k & 1) ? c : s;
    return (k & 2) ? -v : v;
}

__device__ __forceinline__ float npsinf(float xf)
{
    return (float)sin_d((double)xf);
}

// ---------------------------------------------------------------------------
// Materialize np's fp32 intermediates EXACTLY (same arithmetic as round 6/7,
// dW stored TRANSPOSED [i][o] for coalesced forward reads):
// ---------------------------------------------------------------------------
__global__ void precomp_np(const float* __restrict__ lat, const float* __restrict__ U,
                           const float* __restrict__ V0,  const float* __restrict__ Vh,
                           const float* __restrict__ HB,
                           float* __restrict__ dwT, float* __restrict__ dw0,
                           float* __restrict__ fbe)
{
    int bi = blockIdx.x;
    int o  = threadIdx.x;
    if (bi < NHID * B) {
        int l = bi >> 3, b = bi & 7;
        const float* Uo = U + ((size_t)(l + 1) * H + o) * R;
        const float* lb = lat + b * R;
        float t[R];
        #pragma unroll
        for (int r = 0; r < R; ++r) t[r] = Uo[r] * lb[r];   // rounded fp32 mul
        const float* Vb = Vh + (size_t)l * H * R;
        float* dst = dwT + (size_t)(l * B + b) * H * H;     // [i][o]
        for (int i = 0; i < H; ++i) {
            const float* Vi = Vb + (size_t)i * R;
            float acc = 0.f;
            #pragma unroll
            for (int r = 0; r < R; ++r) acc = fmaf(t[r], Vi[r], acc);
            dst[(size_t)i * H + o] = acc;                   // coalesced over o
        }
    } else if (bi < NHID * B + B) {
        int b = bi - NHID * B;
        const float* Uo = U + (size_t)o * R;        // U[0][o][:]
        const float* lb = lat + b * R;
        float t[R];
        #pragma unroll
        for (int r = 0; r < R; ++r) t[r] = Uo[r] * lb[r];
        #pragma unroll
        for (int c = 0; c < C; ++c) {
            float acc = 0.f;
            #pragma unroll
            for (int r = 0; r < R; ++r) acc = fmaf(t[r], V0[c * R + r], acc);
            dw0[((size_t)b * H + o) * 3 + c] = acc;
        }
    } else {
        int b = bi - NHID * B - B;
        const float* lb = lat + b * R;
        for (int lidx = 0; lidx < NHID + 1; ++lidx) {
            const float* hb = HB + ((size_t)lidx * H + o) * R;
            float acc = 0.f;
            #pragma unroll
            for (int r = 0; r < R; ++r) acc = fmaf(lb[r], hb[r], acc);
            fbe[((size_t)lidx * B + b) * H + o] = acc;
        }
    }
}

// Pure bit-exact transpose: wT[l][i][o] = W_hid[l][o][i]
__global__ void transposeW(const float* __restrict__ Wh, float* __restrict__ wT)
{
    int li = blockIdx.x;           // l*H + i
    int o  = threadIdx.x;
    int l = li >> 8, i = li & 255;
    wT[(size_t)li * H + o] = Wh[((size_t)l * H + o) * H + i];
}

// ---------------------------------------------------------------------------
// np-replica forward, coalesced layout, SINGLE LDS act buffer (33.7 KB ->
// 4 blocks/CU, 4 waves/SIMD). Read-all -> barrier -> write-in-place -> barrier
// replaces the round-7 double buffer; accumulators live in registers, so no
// value changes. Arithmetic per output is BIT-IDENTICAL to rounds 6/7:
// single fp32 accumulator, i ascending, fmaf; ((lin+b)+delta)+fb, *30.0f,
// double-rounded sin.
// ---------------------------------------------------------------------------
__launch_bounds__(BLOCK)
__global__ void siren_np(const float* __restrict__ coords,
                         const float* __restrict__ Wf, const float* __restrict__ bf,
                         const float* __restrict__ bh,
                         const float* __restrict__ Wl, const float* __restrict__ bl,
                         const float* __restrict__ wT, const float* __restrict__ dwT,
                         const float* __restrict__ dw0, const float* __restrict__ fbe,
                         float* __restrict__ out)
{
    __shared__ __align__(16) float abuf[PTS * PADA];      // 33,280 B (single buffer)
    __shared__ float cbuf[PTS * 3 + 1];                   // coords tile
    const int tid = threadIdx.x;
    const int og = tid & 63, pg = tid >> 6;
    const int o0 = og * 4, pbase = pg * 8;
    const int p0 = blockIdx.x * PTS;          // global point base
    const int b  = p0 >> 15;                  // N = 2^15; all 32 pts same batch

    if (tid < PTS * 3) cbuf[tid] = coords[(size_t)p0 * 3 + tid];
    __syncthreads();

    // ---- layer 0 ----
    {
        const float* fb0 = fbe + (size_t)(0 * B + b) * H;
        #pragma unroll
        for (int j = 0; j < 4; ++j) {
            const int o = o0 + j;
            const float wf0 = Wf[o * 3 + 0], wf1 = Wf[o * 3 + 1], wf2 = Wf[o * 3 + 2];
            const float* dwo = dw0 + ((size_t)b * H + o) * 3;
            const float dd0 = dwo[0], dd1 = dwo[1], dd2 = dwo[2];
            const float bo = bf[o], fo = fb0[o];
            #pragma unroll
            for (int k = 0; k < 8; ++k) {
                const float x0 = cbuf[(pbase + k) * 3 + 0];
                const float x1 = cbuf[(pbase + k) * 3 + 1];
                const float x2 = cbuf[(pbase + k) * 3 + 2];
                float lin = 0.f;
                lin = fmaf(x0, wf0, lin);
                lin = fmaf(x1, wf1, lin);
                lin = fmaf(x2, wf2, lin);
                lin = lin + bo;
                float dl = 0.f;
                dl = fmaf(x0, dd0, dl);
                dl = fmaf(x1, dd1, dl);
                dl = fmaf(x2, dd2, dl);
                float z = (lin + dl) + fo;
                abuf[(pbase + k) * PADA + o] = npsinf(30.0f * z);
            }
        }
    }
    __syncthreads();

    // ---- hidden layers (in-place act update: read-all / barrier / write) ----
    for (int l = 0; l < NHID; ++l) {
        const float4* Wt4 = (const float4*)(wT  + (size_t)l * H * H);
        const float4* Dt4 = (const float4*)(dwT + (size_t)(l * B + b) * H * H);

        float lacc[4][8], eacc[4][8];
        #pragma unroll
        for (int j = 0; j < 4; ++j)
            #pragma unroll
            for (int k = 0; k < 8; ++k) { lacc[j][k] = 0.f; eacc[j][k] = 0.f; }

        for (int i0 = 0; i0 < H; i0 += 4) {
            float4 av[8];
            #pragma unroll
            for (int k = 0; k < 8; ++k)
                av[k] = *(const float4*)(&abuf[(pbase + k) * PADA + i0]);
            #pragma unroll
            for (int ii = 0; ii < 4; ++ii) {        // i = i0+ii ASCENDING
                const int i = i0 + ii;
                const float4 w4 = Wt4[(size_t)i * 64 + og];
                const float4 d4 = Dt4[(size_t)i * 64 + og];
                const float wj[4] = {w4.x, w4.y, w4.z, w4.w};
                const float dj[4] = {d4.x, d4.y, d4.z, d4.w};
                #pragma unroll
                for (int k = 0; k < 8; ++k) {
                    const float ai = (&av[k].x)[ii];
                    #pragma unroll
                    for (int j = 0; j < 4; ++j) {
                        lacc[j][k] = fmaf(ai, wj[j], lacc[j][k]);
                        eacc[j][k] = fmaf(ai, dj[j], eacc[j][k]);
                    }
                }
            }
        }
        __syncthreads();   // ALL reads of abuf complete before in-place writes
        {
            const float* be  = bh + (size_t)l * H;
            const float* fbl = fbe + (size_t)((l + 1) * B + b) * H;
            const float4 bo4 = *(const float4*)(be + o0);
            const float4 fo4 = *(const float4*)(fbl + o0);
            const float bo[4] = {bo4.x, bo4.y, bo4.z, bo4.w};
            const float fo[4] = {fo4.x, fo4.y, fo4.z, fo4.w};
            #pragma unroll
            for (int k = 0; k < 8; ++k) {
                float4 r;
                #pragma unroll
                for (int j = 0; j < 4; ++j) {
                    float z = ((lacc[j][k] + bo[j]) + eacc[j][k]) + fo[j];
                    (&r.x)[j] = npsinf(30.0f * z);
                }
                *(float4*)(&abuf[(pbase + k) * PADA + o0]) = r;   // same values as r7
            }
        }
        __syncthreads();   // writes visible before next layer's reads
    }

    // ---- final projection (gain ~1): same arithmetic as rounds 6/7 ----
    {
        const int pl = tid >> 3, q = tid & 7;
        const float* ar = abuf + pl * PADA + q * 32;
        const float* wl = Wl + q * 32;
        float s = 0.f;
        #pragma unroll 8
        for (int t = 0; t < 32; ++t) s = fmaf(ar[t], wl[t], s);
        s += __shfl_xor(s, 1);
        s += __shfl_xor(s, 2);
        s += __shfl_xor(s, 4);
        if (q == 0) out[p0 + pl] = s + bl[0];
    }
}

// ---------------------------------------------------------------------------
extern "C" void kernel_launch(void* const* d_in, const int* in_sizes, int n_in,
                              void* d_out, int out_size, void* d_ws, size_t ws_size,
                              hipStream_t stream)
{
    const float* coords = (const float*)d_in[0];
    const float* lat    = (const float*)d_in[1];
    const float* Wf     = (const float*)d_in[2];
    const float* bf     = (const float*)d_in[3];
    const float* Wh     = (const float*)d_in[4];
    const float* bh     = (const float*)d_in[5];
    const float* Wl     = (const float*)d_in[6];
    const float* bl     = (const float*)d_in[7];
    const float* U      = (const float*)d_in[8];
    const float* V0     = (const float*)d_in[9];
    const float* Vh     = (const float*)d_in[10];
    const float* HB     = (const float*)d_in[11];

    float* ws  = (float*)d_ws;   // ~9.46 MB
    float* dwT = ws + OFS_DWT;
    float* wT  = ws + OFS_WT;
    float* dw0 = ws + OFS_DW0;
    float* fbe = ws + OFS_FBE;

    precomp_np<<<NHID * B + B + B, H, 0, stream>>>(lat, U, V0, Vh, HB, dwT, dw0, fbe);
    transposeW<<<NHID * H, H, 0, stream>>>(Wh, wT);
    siren_np<<<(B * N) / PTS, BLOCK, 0, stream>>>(coords, Wf, bf, bh, Wl, bl,
                                                  wT, dwT, dw0, fbe, (float*)d_out);
}

// Round 9
// 3335.456 us; speedup vs baseline: 17.0884x; 1.0189x over previous
//
#include <hip/hip_runtime.h>
#include <math.h>

// Problem constants (must match reference)
constexpr int B = 8, N = 32768, C = 3, H = 256, R = 64, NHID = 4;
constexpr int PTS   = 32;    // points per block
constexpr int BLOCK = 256;   // 64 o-lanes (4 outputs each) x 4 point-groups (8 pts each)
constexpr int PADA  = 260;   // LDS act row stride (multiple of 4 -> aligned float4)
constexpr int PADX  = 68;    // LDS XV row stride (multiple of 4 -> aligned float4)

// Workspace (floats), total ~3.07 MB:
//   ult : [NHID][B][R][H]  (U[l+1][o][r]*lat[b][r]) transposed [r][o] = 524,288
//   wT  : [NHID][H][H]     W_hid transposed [i][o] (bit-exact copy)   = 262,144
//   dw0 : [B][H][3]        layer-0 dW (np-exact, materialized)        =   6,144
//   fbe : [NHID+1][B][H]   FiLM bias                                  =  10,240
constexpr size_t OFS_ULT = 0;
constexpr size_t OFS_WT  = (size_t)NHID * B * R * H;
constexpr size_t OFS_DW0 = OFS_WT + (size_t)NHID * H * H;
constexpr size_t OFS_FBE = OFS_DW0 + (size_t)B * H * 3;

// ---------------------------------------------------------------------------
// fdlibm fp64 sine, error ~1e-16. Models numpy float32 sin as
// (float)sin((double)x). Used at LAYER 0 only (error gain 6.6e4 demands it).
// ---------------------------------------------------------------------------
__device__ __forceinline__ double sin_d(double x)
{
    const double INV_PIO2 = 6.36619772367581382433e-01;
    const double P1  = 1.57079632673412561417e+00;
    const double P1T = 6.07710050650619224932e-11;
    double fn = rint(x * INV_PIO2);
    int n = (int)fn;
    double r = fma(-fn, P1, x);
    r = fma(-fn, P1T, r);
    double z = r * r;
    double ps = fma(z, 1.58969099521155010221e-10, -2.50507602534068634195e-08);
    ps = fma(z, ps, 2.75573137070700676789e-06);
    ps = fma(z, ps, -1.98412698298579493134e-04);
    ps = fma(z, ps, 8.33333333332248946124e-03);
    ps = fma(z, ps, -1.66666666666666324348e-01);
    double s = fma(r * z, ps, r);
    double pc = fma(z, -1.13596475577881948265e-11, 2.08757232129817482790e-09);
    pc = fma(z, pc, -2.75573143513906633035e-07);
    pc = fma(z, pc, 2.48015872894767294178e-05);
    pc = fma(z, pc, -1.38888888888741095749e-03);
    pc = fma(z, pc, 4.16666666666666019037e-02);
    double c = fma(z * z, pc, fma(z, -0.5, 1.0));
    int k = n & 3;
    double v = (k & 1) ? c : s;
    return (k & 2) ? -v : v;
}

__device__ __forceinline__ float npsinf(float xf)
{
    return (float)sin_d((double)xf);
}

// ---------------------------------------------------------------------------
// Hybrid sine for hidden layers: fp64 Cody-Waite argument reduction (phase
// exactness at |x|~100) + fp32 polynomials. Diff vs (float)sin(double) ~1 ulp
// fp32 (~5e-8 rms) -> worst-case out-inject (h0, gain 3930) ~2e-4 rms.
// ---------------------------------------------------------------------------
__device__ __forceinline__ float sinh32(float xf)
{
    const double INV_PIO2 = 6.36619772367581382433e-01;
    const double P1  = 1.57079632673412561417e+00;
    const double P1T = 6.07710050650619224932e-11;
    double xd = (double)xf;
    double fn = rint(xd * INV_PIO2);
    int n = (int)fn;
    double rd = fma(-fn, P1, xd);
    rd = fma(-fn, P1T, rd);
    float r = (float)rd;
    float z = r * r;
    float ps = fmaf(z, 2.7183114939898219e-06f, -1.9839334836096632e-04f);
    ps = fmaf(z, ps, 8.3333293e-03f);
    ps = fmaf(z, ps, -1.6666667e-01f);
    float s = fmaf(r * z, ps, r);
    float pc = fmaf(z, 2.4390448796277409e-05f, -1.3888781739898680e-03f);
    pc = fmaf(z, pc, 4.1666667e-02f);
    float c = fmaf(z * z, pc, fmaf(z, -0.5f, 1.0f));
    int k = n & 3;
    float v = (k & 1) ? c : s;
    return (k & 2) ? -v : v;
}

// ---------------------------------------------------------------------------
// Precompute: ult[l][b][r][o] = U[l+1][o][r]*lat[b][r]  (factored delta),
// dw0 (layer-0 dW, np-exact materialized), fbe (FiLM bias).
// ---------------------------------------------------------------------------
__global__ void precomp_np(const float* __restrict__ lat, const float* __restrict__ U,
                           const float* __restrict__ V0,
                           const float* __restrict__ HB,
                           float* __restrict__ ult, float* __restrict__ dw0,
                           float* __restrict__ fbe)
{
    int bi = blockIdx.x;
    int o  = threadIdx.x;
    if (bi < NHID * B) {
        int l = bi >> 3, b = bi & 7;
        const float* Uo = U + ((size_t)(l + 1) * H + o) * R;
        const float* lb = lat + b * R;
        float* dst = ult + (size_t)(l * B + b) * R * H;   // [r][o]
        #pragma unroll
        for (int r = 0; r < R; ++r)
            dst[(size_t)r * H + o] = Uo[r] * lb[r];       // rounded fp32 mul (np order)
    } else if (bi < NHID * B + B) {
        int b = bi - NHID * B;
        const float* Uo = U + (size_t)o * R;        // U[0][o][:]
        const float* lb = lat + b * R;
        float t[R];
        #pragma unroll
        for (int r = 0; r < R; ++r) t[r] = Uo[r] * lb[r];
        #pragma unroll
        for (int c = 0; c < C; ++c) {
            float acc = 0.f;
            #pragma unroll
            for (int r = 0; r < R; ++r) acc = fmaf(t[r], V0[c * R + r], acc);
            dw0[((size_t)b * H + o) * 3 + c] = acc;
        }
    } else {
        int b = bi - NHID * B - B;
        const float* lb = lat + b * R;
        for (int lidx = 0; lidx < NHID + 1; ++lidx) {
            const float* hb = HB + ((size_t)lidx * H + o) * R;
            float acc = 0.f;
            #pragma unroll
            for (int r = 0; r < R; ++r) acc = fmaf(lb[r], hb[r], acc);
            fbe[((size_t)lidx * B + b) * H + o] = acc;
        }
    }
}

// Pure bit-exact transpose: wT[l][i][o] = W_hid[l][o][i]
__global__ void transposeW(const float* __restrict__ Wh, float* __restrict__ wT)
{
    int li = blockIdx.x;           // l*H + i
    int o  = threadIdx.x;
    int l = li >> 8, i = li & 255;
    wT[(size_t)li * H + o] = Wh[((size_t)l * H + o) * H + i];
}

// ---------------------------------------------------------------------------
// np-replica forward. lin GEMM is BIT-IDENTICAL to rounds 6-8 (single fp32
// accumulator, i ascending, fmaf, same wT stream). delta is now factored:
//   phase A: XV[n][r] = sum_i act[n][i] * V[l][i][r]     (fp32, i asc)
//   phase B: eacc[o]  = sum_r XV[n][r] * ult[r][o]       (fp32, r asc)
// then z = ((lin + b) + delta) + fb, *30.0f, sin (L0 fp64; hidden hybrid).
// ---------------------------------------------------------------------------
__launch_bounds__(BLOCK)
__global__ void siren_np(const float* __restrict__ coords,
                         const float* __restrict__ Wf, const float* __restrict__ bf,
                         const float* __restrict__ bh,
                         const float* __restrict__ Wl, const float* __restrict__ bl,
                         const float* __restrict__ wT, const float* __restrict__ ult,
                         const float* __restrict__ Vh,
                         const float* __restrict__ dw0, const float* __restrict__ fbe,
                         float* __restrict__ out)
{
    __shared__ __align__(16) float abuf[PTS * PADA];   // 33,280 B
    __shared__ __align__(16) float xvbuf[PTS * PADX];  //  8,704 B
    __shared__ float cbuf[PTS * 3 + 1];
    const int tid = threadIdx.x;
    const int og = tid & 63, pg = tid >> 6;
    const int o0 = og * 4, pbase = pg * 8;
    const int p0 = blockIdx.x * PTS;          // global point base
    const int b  = p0 >> 15;                  // N = 2^15; all 32 pts same batch

    if (tid < PTS * 3) cbuf[tid] = coords[(size_t)p0 * 3 + tid];
    __syncthreads();

    // ---- layer 0 (bit-identical to rounds 6-8) ----
    {
        const float* fb0 = fbe + (size_t)(0 * B + b) * H;
        #pragma unroll
        for (int j = 0; j < 4; ++j) {
            const int o = o0 + j;
            const float wf0 = Wf[o * 3 + 0], wf1 = Wf[o * 3 + 1], wf2 = Wf[o * 3 + 2];
            const float* dwo = dw0 + ((size_t)b * H + o) * 3;
            const float dd0 = dwo[0], dd1 = dwo[1], dd2 = dwo[2];
            const float bo = bf[o], fo = fb0[o];
            #pragma unroll
            for (int k = 0; k < 8; ++k) {
                const float x0 = cbuf[(pbase + k) * 3 + 0];
                const float x1 = cbuf[(pbase + k) * 3 + 1];
                const float x2 = cbuf[(pbase + k) * 3 + 2];
                float lin = 0.f;
                lin = fmaf(x0, wf0, lin);
                lin = fmaf(x1, wf1, lin);
                lin = fmaf(x2, wf2, lin);
                lin = lin + bo;
                float dl = 0.f;
                dl = fmaf(x0, dd0, dl);
                dl = fmaf(x1, dd1, dl);
                dl = fmaf(x2, dd2, dl);
                float z = (lin + dl) + fo;
                abuf[(pbase + k) * PADA + o] = npsinf(30.0f * z);
            }
        }
    }
    __syncthreads();

    // ---- hidden layers ----
    for (int l = 0; l < NHID; ++l) {
        // phase A: XV[n][r] = sum_i act[n][i]*V[l][i][r]  (thread: n=tid>>3, 8 r's)
        {
            const int xn = tid >> 3, r0 = (tid & 7) * 8;
            const float* Vb = Vh + (size_t)l * H * R;     // [i][r]
            float a8[8] = {0.f,0.f,0.f,0.f,0.f,0.f,0.f,0.f};
            for (int i0 = 0; i0 < H; i0 += 4) {
                float4 a4 = *(const float4*)(&abuf[xn * PADA + i0]);
                #pragma unroll
                for (int ii = 0; ii < 4; ++ii) {
                    const float ai = (&a4.x)[ii];
                    float4 va = *(const float4*)(Vb + (size_t)(i0 + ii) * R + r0);
                    float4 vb = *(const float4*)(Vb + (size_t)(i0 + ii) * R + r0 + 4);
                    a8[0] = fmaf(ai, va.x, a8[0]); a8[1] = fmaf(ai, va.y, a8[1]);
                    a8[2] = fmaf(ai, va.z, a8[2]); a8[3] = fmaf(ai, va.w, a8[3]);
                    a8[4] = fmaf(ai, vb.x, a8[4]); a8[5] = fmaf(ai, vb.y, a8[5]);
                    a8[6] = fmaf(ai, vb.z, a8[6]); a8[7] = fmaf(ai, vb.w, a8[7]);
                }
            }
            *(float4*)(&xvbuf[xn * PADX + r0])     = make_float4(a8[0], a8[1], a8[2], a8[3]);
            *(float4*)(&xvbuf[xn * PADX + r0 + 4]) = make_float4(a8[4], a8[5], a8[6], a8[7]);
        }
        __syncthreads();

        // phase B: delta (K=64 over ult) + lin (K=256 over wT, np-exact)
        float eacc[4][8];
        #pragma unroll
        for (int j = 0; j < 4; ++j)
            #pragma unroll
            for (int k = 0; k < 8; ++k) eacc[j][k] = 0.f;
        {
            const float4* UT4 = (const float4*)(ult + (size_t)(l * B + b) * R * H);
            for (int r0 = 0; r0 < R; r0 += 4) {
                float4 xv4[8];
                #pragma unroll
                for (int k = 0; k < 8; ++k)
                    xv4[k] = *(const float4*)(&xvbuf[(pbase + k) * PADX + r0]);
                #pragma unroll
                for (int rr = 0; rr < 4; ++rr) {       // r ASCENDING
                    const float4 u4 = UT4[(size_t)(r0 + rr) * 64 + og];
                    const float uj[4] = {u4.x, u4.y, u4.z, u4.w};
                    #pragma unroll
                    for (int k = 0; k < 8; ++k) {
                        const float xv = (&xv4[k].x)[rr];
                        #pragma unroll
                        for (int j = 0; j < 4; ++j)
                            eacc[j][k] = fmaf(xv, uj[j], eacc[j][k]);
                    }
                }
            }
        }
        float lacc[4][8];
        #pragma unroll
        for (int j = 0; j < 4; ++j)
            #pragma unroll
            for (int k = 0; k < 8; ++k) lacc[j][k] = 0.f;
        {
            const float4* Wt4 = (const float4*)(wT + (size_t)l * H * H);
            for (int i0 = 0; i0 < H; i0 += 4) {
                float4 av[8];
                #pragma unroll
                for (int k = 0; k < 8; ++k)
                    av[k] = *(const float4*)(&abuf[(pbase + k) * PADA + i0]);
                #pragma unroll
                for (int ii = 0; ii < 4; ++ii) {        // i ASCENDING (np sgemm)
                    const int i = i0 + ii;
                    const float4 w4 = Wt4[(size_t)i * 64 + og];
                    const float wj[4] = {w4.x, w4.y, w4.z, w4.w};
                    #pragma unroll
                    for (int k = 0; k < 8; ++k) {
                        const float ai = (&av[k].x)[ii];
                        #pragma unroll
                        for (int j = 0; j < 4; ++j)
                            lacc[j][k] = fmaf(ai, wj[j], lacc[j][k]);
                    }
                }
            }
        }
        __syncthreads();   // ALL reads of abuf/xvbuf complete before in-place writes
        {
            const float* be  = bh + (size_t)l * H;
            const float* fbl = fbe + (size_t)((l + 1) * B + b) * H;
            const float4 bo4 = *(const float4*)(be + o0);
            const float4 fo4 = *(const float4*)(fbl + o0);
            const float bo[4] = {bo4.x, bo4.y, bo4.z, bo4.w};
            const float fo[4] = {fo4.x, fo4.y, fo4.z, fo4.w};
            #pragma unroll
            for (int k = 0; k < 8; ++k) {
                float4 rv;
                #pragma unroll
                for (int j = 0; j < 4; ++j) {
                    float z = ((lacc[j][k] + bo[j]) + eacc[j][k]) + fo[j];
                    (&rv.x)[j] = sinh32(30.0f * z);
                }
                *(float4*)(&abuf[(pbase + k) * PADA + o0]) = rv;
            }
        }
        __syncthreads();   // writes visible before next layer's reads
    }

    // ---- final projection (gain ~1): same arithmetic as rounds 6-8 ----
    {
        const int pl = tid >> 3, q = tid & 7;
        const float* ar = abuf + pl * PADA + q * 32;
        const float* wl = Wl + q * 32;
        float s = 0.f;
        #pragma unroll 8
        for (int t = 0; t < 32; ++t) s = fmaf(ar[t], wl[t], s);
        s += __shfl_xor(s, 1);
        s += __shfl_xor(s, 2);
        s += __shfl_xor(s, 4);
        if (q == 0) out[p0 + pl] = s + bl[0];
    }
}

// ---------------------------------------------------------------------------
extern "C" void kernel_launch(void* const* d_in, const int* in_sizes, int n_in,
                              void* d_out, int out_size, void* d_ws, size_t ws_size,
                              hipStream_t stream)
{
    const float* coords = (const float*)d_in[0];
    const float* lat    = (const float*)d_in[1];
    const float* Wf     = (const float*)d_in[2];
    const float* bf     = (const float*)d_in[3];
    const float* Wh     = (const float*)d_in[4];
    const float* bh     = (const float*)d_in[5];
    const float* Wl     = (const float*)d_in[6];
    const float* bl     = (const float*)d_in[7];
    const float* U      = (const float*)d_in[8];
    const float* V0     = (const float*)d_in[9];
    const float* Vh     = (const float*)d_in[10];
    const float* HB     = (const float*)d_in[11];

    float* ws  = (float*)d_ws;   // ~3.07 MB
    float* ult = ws + OFS_ULT;
    float* wT  = ws + OFS_WT;
    float* dw0 = ws + OFS_DW0;
    float* fbe = ws + OFS_FBE;

    precomp_np<<<NHID * B + B + B, H, 0, stream>>>(lat, U, V0, HB, ult, dw0, fbe);
    transposeW<<<NHID * H, H, 0, stream>>>(Wh, wT);
    siren_np<<<(B * N) / PTS, BLOCK, 0, stream>>>(coords, Wf, bf, bh, Wl, bl,
                                                  wT, ult, Vh, dw0, fbe, (float*)d_out);
}